// Round 7
// baseline (210.362 us; speedup 1.0000x reference)
//
#include <hip/hip_runtime.h>
#include <stdint.h>

// SymmetricContraction (MACE) on MI355X — symmetrized monomials, 3-kernel split.
//
// out[b,c,m] = sum_{a<=b<=cc} x_a x_b x_cc*T3 + sum_{a<=b} x_a x_b*T2 + sum_a x_a*T1
// Horner: out = sum_a x_a*( T1[a] + sum_{b>=a} x_b*( T2[ab] + sum_{cc>=b} x_cc*T3 ) )
// Irreps fused into float4 slots (0e | 1o m=0..2).
//
// R7 (from counters): apply is LDS-pipe-bound and the dominant term is the
// per-WAVE coefficient broadcast (968 b128 / 128 nodes). Now: 64-thread
// blocks (1 wave), 4 nodes/thread, x packed as float4 rows in LDS -> the
// 968-coef broadcast serves 256 nodes (2x amortization), total waves halve.
// Math on v2f pairs (v_pk_fma_f32), lo=(n0,n1) hi=(n2,n3).

#define BN 2048
#define CN 128
#define EN 10

#define NT3 816   // #sorted triples a<=b<=cc in [0,16)
#define NT2 136   // #sorted pairs a<=b
#define NTT (NT3 + NT2 + 16)   // 968 fused table entries (float4 each)
#define K3_0 23
#define K3_1 33
#define K2_0 4
#define K2_1 5

// ws layout (float offsets)
#define U3S0_OFF 0                          // [23][816]
#define U3S1_OFF (K3_0*NT3)                 // [3][33][816]
#define U2S0_OFF (U3S1_OFF + 3*K3_1*NT3)    // [4][136]
#define U2S1_OFF (U2S0_OFF + K2_0*NT2)      // [3][5][136]
#define LISTS_OFF (U2S1_OFF + 3*K2_1*NT2)   // int[10][2048]
#define CNT_OFF (LISTS_OFF + EN*BN)         // int[10]
#define TALL_OFF (((CNT_OFF + EN) + 3) & ~3)        // float4[1280][968]
#define WS_NEED_BYTES ((size_t)(TALL_OFF + (size_t)EN*CN*NTT*4) * 4)

#define PREP_TOT (K3_0*NT3 + 3*K3_1*NT3 + K2_0*NT2 + 3*K2_1*NT2)  // 102136
#define PREP_BLOCKS ((PREP_TOT + 255) / 256)                       // 400

typedef float v2f __attribute__((ext_vector_type(2)));
#define FMA2(a, b, c) __builtin_elementwise_fma((a), (b), (c))
static __device__ __forceinline__ v2f splat2(float v) { v2f r; r.x = v; r.y = v; return r; }

__global__ __launch_bounds__(256) void prep_sym(
    const float* __restrict__ U3_0, const float* __restrict__ U2_0,
    const float* __restrict__ U3_1, const float* __restrict__ U2_1,
    const float* __restrict__ yg, float* __restrict__ ws)
{
    const int bid = blockIdx.x, tid = threadIdx.x;
    if (bid < PREP_BLOCKS) {
        const int N0 = K3_0*NT3, N1 = 3*K3_1*NT3, P0 = K2_0*NT2;
        const int it = bid*256 + tid;
        if (it >= PREP_TOT) return;
        if (it < N0 + N1) {
            const float* U3; int m, k, K, t, dst;
            if (it < N0) { U3 = U3_0; K = K3_0; m = 0; k = it / NT3; t = it - k*NT3; dst = U3S0_OFF + it; }
            else { int r = it - N0; U3 = U3_1; K = K3_1; int mk = r / NT3; t = r - mk*NT3;
                   m = mk / K3_1; k = mk - m*K3_1; dst = U3S1_OFF + r; }
            // unrank t -> (a<=b<=cc), lexicographic (matches sc_apply loop order)
            int a = 0, rem = t;
            while (rem >= ((16-a)*(17-a))/2) { rem -= ((16-a)*(17-a))/2; ++a; }
            int b = a;
            while (rem >= 16-b) { rem -= 16-b; ++b; }
            const int cc = b + rem;
            #define AT3(i,j,l) U3[(size_t)(((m*16+(i))*16+(j))*16+(l))*K + k]
            float D = AT3(a,b,cc) + AT3(a,cc,b) + AT3(b,a,cc)
                    + AT3(b,cc,a) + AT3(cc,a,b) + AT3(cc,b,a);
            #undef AT3
            const int eq = (a==b) + (b==cc);
            D *= (eq==2) ? (1.f/6.f) : (eq==1) ? 0.5f : 1.f;
            ws[dst] = D;
        } else {
            const int it2 = it - (N0+N1);
            const float* U2; int m, k, K, pr, dst;
            if (it2 < P0) { U2 = U2_0; K = K2_0; m = 0; k = it2 / NT2; pr = it2 - k*NT2; dst = U2S0_OFF + it2; }
            else { int r = it2 - P0; U2 = U2_1; K = K2_1; int mk = r / NT2; pr = r - mk*NT2;
                   m = mk / K2_1; k = mk - m*K2_1; dst = U2S1_OFF + r; }
            int a = 0, rem = pr;
            while (rem >= 16-a) { rem -= 16-a; ++a; }
            const int b = a + rem;
            float D = U2[(size_t)((m*16+a)*16+b)*K + k]
                    + U2[(size_t)((m*16+b)*16+a)*K + k];
            if (a == b) D *= 0.5f;
            ws[dst] = D;
        }
    } else if (bid < PREP_BLOCKS + EN) {
        const int e = bid - PREP_BLOCKS;
        __shared__ int lcnt;
        if (tid == 0) lcnt = 0;
        __syncthreads();
        int* lists = (int*)(ws + LISTS_OFF);
        for (int b = tid; b < BN; b += 256) {
            if (yg[b*EN + e] > 0.5f) {
                int p = atomicAdd(&lcnt, 1);
                lists[e*BN + p] = b;
            }
        }
        __syncthreads();
        if (tid == 0) ((int*)(ws + CNT_OFF))[e] = lcnt;
    }
}

// ---- fused tables: block=(8-g chunk, e), thread=c ------------------------
__global__ __launch_bounds__(128) void sc_build(
    const float* __restrict__ usym, float4* __restrict__ tall,
    const float* __restrict__ U1_0, const float* __restrict__ U1_1,
    const float* __restrict__ W3_0, const float* __restrict__ W2_0, const float* __restrict__ W1_0,
    const float* __restrict__ W3_1, const float* __restrict__ W2_1, const float* __restrict__ W1_1)
{
    const int g0 = blockIdx.x * 8;
    const int e = blockIdx.y;
    const int c = threadIdx.x;
    float4* out4 = tall + (size_t)(e*CN + c)*NTT;

    if (g0 < NT3) {
        float w0[K3_0], w1[K3_1];
#pragma unroll
        for (int k = 0; k < K3_0; ++k) w0[k] = W3_0[(e*K3_0 + k)*CN + c];
#pragma unroll
        for (int k = 0; k < K3_1; ++k) w1[k] = W3_1[(e*K3_1 + k)*CN + c];
        const float* u0 = usym + U3S0_OFF;
        const float* u1 = usym + U3S1_OFF;
#pragma unroll 2
        for (int j = 0; j < 8; ++j) {
            const int g = g0 + j;
            float a0 = 0.f, a1 = 0.f, a2 = 0.f, a3 = 0.f;
#pragma unroll
            for (int k = 0; k < K3_0; ++k) a0 = fmaf(u0[k*NT3 + g], w0[k], a0);
#pragma unroll
            for (int k = 0; k < K3_1; ++k) {
                a1 = fmaf(u1[k*NT3 + g], w1[k], a1);
                a2 = fmaf(u1[(K3_1 + k)*NT3 + g], w1[k], a2);
                a3 = fmaf(u1[(2*K3_1 + k)*NT3 + g], w1[k], a3);
            }
            out4[g] = make_float4(a0, a1, a2, a3);
        }
    } else if (g0 < NT3 + NT2) {
        float w0[K2_0], w1[K2_1];
#pragma unroll
        for (int k = 0; k < K2_0; ++k) w0[k] = W2_0[(e*K2_0 + k)*CN + c];
#pragma unroll
        for (int k = 0; k < K2_1; ++k) w1[k] = W2_1[(e*K2_1 + k)*CN + c];
        const float* u0 = usym + U2S0_OFF;
        const float* u1 = usym + U2S1_OFF;
#pragma unroll
        for (int j = 0; j < 8; ++j) {
            const int g = g0 + j;
            const int pr = g - NT3;
            float a0 = 0.f, a1 = 0.f, a2 = 0.f, a3 = 0.f;
#pragma unroll
            for (int k = 0; k < K2_0; ++k) a0 = fmaf(u0[k*NT2 + pr], w0[k], a0);
#pragma unroll
            for (int k = 0; k < K2_1; ++k) {
                a1 = fmaf(u1[k*NT2 + pr], w1[k], a1);
                a2 = fmaf(u1[(K2_1 + k)*NT2 + pr], w1[k], a2);
                a3 = fmaf(u1[(2*K2_1 + k)*NT2 + pr], w1[k], a3);
            }
            out4[g] = make_float4(a0, a1, a2, a3);
        }
    } else {
        const float w10 = W1_0[e*CN + c];
        const float w11 = W1_1[e*CN + c];
#pragma unroll
        for (int j = 0; j < 8; ++j) {
            const int g = g0 + j;
            const int a = g - (NT3 + NT2);
            out4[g] = make_float4(U1_0[a]*w10, U1_1[a]*w11,
                                  U1_1[16+a]*w11, U1_1[32+a]*w11);
        }
    }
}

// ---- node loop: 1 wave/block, 4 nodes/thread. Coef broadcast (b128) serves
// 256 nodes; x rows are float4-packed (one b128 = 4 nodes' x_i). pk-fma math.
__global__ __launch_bounds__(64) void sc_apply(
    const float* __restrict__ xg, const float* __restrict__ ws,
    float* __restrict__ outg)
{
    const int c = blockIdx.x, e = blockIdx.y, tid = threadIdx.x;
    __shared__ float4 Ts[NTT];      // 15488 B
    __shared__ float4 xs[16*64];    // 16384 B: xs[i*64+t] = x_i of t's 4 nodes

    const float4* __restrict__ tG =
        (const float4*)(ws + TALL_OFF) + (size_t)(e*CN + c)*NTT;
    for (int i = tid; i < NTT; i += 64) Ts[i] = tG[i];

    const int* lists = (const int*)(ws + LISTS_OFF) + e*BN;
    const int cnt = ((const int*)(ws + CNT_OFF))[e];
    __syncthreads();

    for (int base = 0; base < cnt; base += 256) {
        const int s0 = base + 4*tid;
        const bool a0v = s0 < cnt, a1v = s0+1 < cnt, a2v = s0+2 < cnt, a3v = s0+3 < cnt;
        const int n0 = lists[a0v ? s0   : 0];
        const int n1 = lists[a1v ? s0+1 : 0];
        const int n2 = lists[a2v ? s0+2 : 0];
        const int n3 = lists[a3v ? s0+3 : 0];
        const float4* p0 = (const float4*)(xg + ((size_t)n0*CN + c)*16);
        const float4* p1 = (const float4*)(xg + ((size_t)n1*CN + c)*16);
        const float4* p2 = (const float4*)(xg + ((size_t)n2*CN + c)*16);
        const float4* p3 = (const float4*)(xg + ((size_t)n3*CN + c)*16);
#pragma unroll
        for (int d = 0; d < 4; ++d) {
            const float4 v0 = p0[d], v1 = p1[d], v2 = p2[d], v3 = p3[d];
            xs[(4*d+0)*64+tid] = make_float4(v0.x, v1.x, v2.x, v3.x);
            xs[(4*d+1)*64+tid] = make_float4(v0.y, v1.y, v2.y, v3.y);
            xs[(4*d+2)*64+tid] = make_float4(v0.z, v1.z, v2.z, v3.z);
            xs[(4*d+3)*64+tid] = make_float4(v0.w, v1.w, v2.w, v3.w);
        }
        // single wave: ds write->read ordering handled by lgkmcnt; no barrier.

        v2f acc0l = splat2(0.f), acc0h = acc0l, acc1l = acc0l, acc1h = acc0l;
        v2f acc2l = acc0l, acc2h = acc0l, acc3l = acc0l, acc3h = acc0l;
        int t3 = 0, t2 = NT3;
#pragma unroll 1
        for (int a = 0; a < 16; ++a) {
            const float4 xa4 = xs[a*64+tid];
            const v2f xal = {xa4.x, xa4.y}, xah = {xa4.z, xa4.w};
            const float4 t1v = Ts[NT3 + NT2 + a];
            v2f tP0l = splat2(t1v.x), tP0h = tP0l;
            v2f tP1l = splat2(t1v.y), tP1h = tP1l;
            v2f tP2l = splat2(t1v.z), tP2h = tP2l;
            v2f tP3l = splat2(t1v.w), tP3h = tP3l;
#pragma unroll 1
            for (int b = a; b < 16; ++b) {
                const float4 xb4 = xs[b*64+tid];
                const v2f xbl = {xb4.x, xb4.y}, xbh = {xb4.z, xb4.w};
                const float4 c2v = Ts[t2]; ++t2;
                v2f tB0l = splat2(c2v.x), tB0h = tB0l;
                v2f tB1l = splat2(c2v.y), tB1h = tB1l;
                v2f tB2l = splat2(c2v.z), tB2h = tB2l;
                v2f tB3l = splat2(c2v.w), tB3h = tB3l;
#pragma unroll 4
                for (int cc = b; cc < 16; ++cc) {
                    const float4 xc4 = xs[cc*64+tid];
                    const v2f xcl = {xc4.x, xc4.y}, xch = {xc4.z, xc4.w};
                    const float4 c3v = Ts[t3]; ++t3;
                    tB0l = FMA2(splat2(c3v.x), xcl, tB0l);
                    tB0h = FMA2(splat2(c3v.x), xch, tB0h);
                    tB1l = FMA2(splat2(c3v.y), xcl, tB1l);
                    tB1h = FMA2(splat2(c3v.y), xch, tB1h);
                    tB2l = FMA2(splat2(c3v.z), xcl, tB2l);
                    tB2h = FMA2(splat2(c3v.z), xch, tB2h);
                    tB3l = FMA2(splat2(c3v.w), xcl, tB3l);
                    tB3h = FMA2(splat2(c3v.w), xch, tB3h);
                }
                tP0l = FMA2(tB0l, xbl, tP0l); tP0h = FMA2(tB0h, xbh, tP0h);
                tP1l = FMA2(tB1l, xbl, tP1l); tP1h = FMA2(tB1h, xbh, tP1h);
                tP2l = FMA2(tB2l, xbl, tP2l); tP2h = FMA2(tB2h, xbh, tP2h);
                tP3l = FMA2(tB3l, xbl, tP3l); tP3h = FMA2(tB3h, xbh, tP3h);
            }
            acc0l = FMA2(tP0l, xal, acc0l); acc0h = FMA2(tP0h, xah, acc0h);
            acc1l = FMA2(tP1l, xal, acc1l); acc1h = FMA2(tP1h, xah, acc1h);
            acc2l = FMA2(tP2l, xal, acc2l); acc2h = FMA2(tP2h, xah, acc2h);
            acc3l = FMA2(tP3l, xal, acc3l); acc3h = FMA2(tP3h, xah, acc3h);
        }
        if (a0v) {
            float* o = outg + (size_t)n0*512;
            o[c] = acc0l.x;
            o[128 + c*3 + 0] = acc1l.x; o[128 + c*3 + 1] = acc2l.x; o[128 + c*3 + 2] = acc3l.x;
        }
        if (a1v) {
            float* o = outg + (size_t)n1*512;
            o[c] = acc0l.y;
            o[128 + c*3 + 0] = acc1l.y; o[128 + c*3 + 1] = acc2l.y; o[128 + c*3 + 2] = acc3l.y;
        }
        if (a2v) {
            float* o = outg + (size_t)n2*512;
            o[c] = acc0h.x;
            o[128 + c*3 + 0] = acc1h.x; o[128 + c*3 + 1] = acc2h.x; o[128 + c*3 + 2] = acc3h.x;
        }
        if (a3v) {
            float* o = outg + (size_t)n3*512;
            o[c] = acc0h.y;
            o[128 + c*3 + 0] = acc1h.y; o[128 + c*3 + 1] = acc2h.y; o[128 + c*3 + 2] = acc3h.y;
        }
    }
}

// ---- fallback (proven fused kernel): used only if ws is too small ---------
__global__ __launch_bounds__(128) void sc_main_fused(
    const float* __restrict__ xg,
    const float* __restrict__ U1_0, const float* __restrict__ U1_1,
    const float* __restrict__ W3_0, const float* __restrict__ W2_0, const float* __restrict__ W1_0,
    const float* __restrict__ W3_1, const float* __restrict__ W2_1, const float* __restrict__ W1_1,
    const float* __restrict__ ws, float* __restrict__ outg)
{
    const int c = blockIdx.x, e = blockIdx.y, tid = threadIdx.x;
    __shared__ float4 T3s[NT3];
    __shared__ float4 T2s[NT2];
    __shared__ float4 T1s[16];
    __shared__ float xs0[16*128];
    __shared__ float xs1[16*128];
    __shared__ float wk30s[K3_0], wk31s[K3_1], wk20s[K2_0], wk21s[K2_1];

    if (tid < K3_0) wk30s[tid] = W3_0[(e*K3_0 + tid)*CN + c];
    if (tid >= 32 && tid < 32 + K3_1) wk31s[tid-32] = W3_1[(e*K3_1 + (tid-32))*CN + c];
    if (tid >= 72 && tid < 72 + K2_0) wk20s[tid-72] = W2_0[(e*K2_0 + (tid-72))*CN + c];
    if (tid >= 80 && tid < 80 + K2_1) wk21s[tid-80] = W2_1[(e*K2_1 + (tid-80))*CN + c];
    __syncthreads();

    const float* u3s0 = ws + U3S0_OFF;
    const float* u3s1 = ws + U3S1_OFF;
    for (int g = tid; g < NT3/4; g += 128) {
        float4 A0 = make_float4(0,0,0,0), A1 = A0, A2 = A0, A3 = A0;
#pragma unroll
        for (int k = 0; k < K3_0; ++k) {
            const float w = wk30s[k];
            const float4 u = ((const float4*)(u3s0 + k*NT3))[g];
            A0.x = fmaf(u.x, w, A0.x); A0.y = fmaf(u.y, w, A0.y);
            A0.z = fmaf(u.z, w, A0.z); A0.w = fmaf(u.w, w, A0.w);
        }
#pragma unroll 8
        for (int k = 0; k < K3_1; ++k) {
            const float w = wk31s[k];
            const float4 ua = ((const float4*)(u3s1 + k*NT3))[g];
            A1.x = fmaf(ua.x, w, A1.x); A1.y = fmaf(ua.y, w, A1.y);
            A1.z = fmaf(ua.z, w, A1.z); A1.w = fmaf(ua.w, w, A1.w);
            const float4 ub = ((const float4*)(u3s1 + (K3_1 + k)*NT3))[g];
            A2.x = fmaf(ub.x, w, A2.x); A2.y = fmaf(ub.y, w, A2.y);
            A2.z = fmaf(ub.z, w, A2.z); A2.w = fmaf(ub.w, w, A2.w);
            const float4 uc = ((const float4*)(u3s1 + (2*K3_1 + k)*NT3))[g];
            A3.x = fmaf(uc.x, w, A3.x); A3.y = fmaf(uc.y, w, A3.y);
            A3.z = fmaf(uc.z, w, A3.z); A3.w = fmaf(uc.w, w, A3.w);
        }
        T3s[4*g+0] = make_float4(A0.x, A1.x, A2.x, A3.x);
        T3s[4*g+1] = make_float4(A0.y, A1.y, A2.y, A3.y);
        T3s[4*g+2] = make_float4(A0.z, A1.z, A2.z, A3.z);
        T3s[4*g+3] = make_float4(A0.w, A1.w, A2.w, A3.w);
    }
    const float* u2s0 = ws + U2S0_OFF;
    const float* u2s1 = ws + U2S1_OFF;
    for (int g = tid; g < NT2/4; g += 128) {
        float4 A0 = make_float4(0,0,0,0), A1 = A0, A2 = A0, A3 = A0;
#pragma unroll
        for (int k = 0; k < K2_0; ++k) {
            const float w = wk20s[k];
            const float4 u = ((const float4*)(u2s0 + k*NT2))[g];
            A0.x = fmaf(u.x, w, A0.x); A0.y = fmaf(u.y, w, A0.y);
            A0.z = fmaf(u.z, w, A0.z); A0.w = fmaf(u.w, w, A0.w);
        }
#pragma unroll
        for (int k = 0; k < K2_1; ++k) {
            const float w = wk21s[k];
            const float4 ua = ((const float4*)(u2s1 + k*NT2))[g];
            A1.x = fmaf(ua.x, w, A1.x); A1.y = fmaf(ua.y, w, A1.y);
            A1.z = fmaf(ua.z, w, A1.z); A1.w = fmaf(ua.w, w, A1.w);
            const float4 ub = ((const float4*)(u2s1 + (K2_1 + k)*NT2))[g];
            A2.x = fmaf(ub.x, w, A2.x); A2.y = fmaf(ub.y, w, A2.y);
            A2.z = fmaf(ub.z, w, A2.z); A2.w = fmaf(ub.w, w, A2.w);
            const float4 uc = ((const float4*)(u2s1 + (2*K2_1 + k)*NT2))[g];
            A3.x = fmaf(uc.x, w, A3.x); A3.y = fmaf(uc.y, w, A3.y);
            A3.z = fmaf(uc.z, w, A3.z); A3.w = fmaf(uc.w, w, A3.w);
        }
        T2s[4*g+0] = make_float4(A0.x, A1.x, A2.x, A3.x);
        T2s[4*g+1] = make_float4(A0.y, A1.y, A2.y, A3.y);
        T2s[4*g+2] = make_float4(A0.z, A1.z, A2.z, A3.z);
        T2s[4*g+3] = make_float4(A0.w, A1.w, A2.w, A3.w);
    }
    if (tid < 16) {
        const float wk10 = W1_0[e*CN + c];
        const float wk11 = W1_1[e*CN + c];
        const int j = tid;
        T1s[j] = make_float4(U1_0[j]*wk10, U1_1[j]*wk11,
                             U1_1[16+j]*wk11, U1_1[32+j]*wk11);
    }

    const int* lists = (const int*)(ws + LISTS_OFF) + e*BN;
    const int cnt = ((const int*)(ws + CNT_OFF))[e];
    __syncthreads();

    for (int base = 0; base < cnt; base += 256) {
        const int s0 = base + tid, s1 = base + tid + 128;
        const bool act0 = s0 < cnt, act1 = s1 < cnt;
        const int n0 = lists[act0 ? s0 : 0];
        const int n1 = lists[act1 ? s1 : 0];
        const float4* p0 = (const float4*)(xg + ((size_t)n0*CN + c)*16);
        const float4* p1 = (const float4*)(xg + ((size_t)n1*CN + c)*16);
#pragma unroll
        for (int d = 0; d < 4; ++d) {
            const float4 v0 = p0[d]; const float4 v1 = p1[d];
            xs0[(4*d+0)*128+tid] = v0.x; xs0[(4*d+1)*128+tid] = v0.y;
            xs0[(4*d+2)*128+tid] = v0.z; xs0[(4*d+3)*128+tid] = v0.w;
            xs1[(4*d+0)*128+tid] = v1.x; xs1[(4*d+1)*128+tid] = v1.y;
            xs1[(4*d+2)*128+tid] = v1.z; xs1[(4*d+3)*128+tid] = v1.w;
        }
        float4 acc0 = make_float4(0,0,0,0), acc1 = acc0;
        int t3 = 0, t2i = 0;
#pragma unroll 1
        for (int a = 0; a < 16; ++a) {
            const float xa0 = xs0[a*128+tid];
            const float xa1 = xs1[a*128+tid];
            float4 tP0 = T1s[a], tP1 = tP0;
#pragma unroll 1
            for (int b = a; b < 16; ++b) {
                const float xb0 = xs0[b*128+tid];
                const float xb1 = xs1[b*128+tid];
                const float4 c2v = T2s[t2i]; ++t2i;
                float4 tB0 = c2v, tB1 = c2v;
#pragma unroll 4
                for (int cc = b; cc < 16; ++cc) {
                    const float xc0 = xs0[cc*128+tid];
                    const float xc1 = xs1[cc*128+tid];
                    const float4 c3v = T3s[t3]; ++t3;
                    tB0.x = fmaf(c3v.x, xc0, tB0.x); tB0.y = fmaf(c3v.y, xc0, tB0.y);
                    tB0.z = fmaf(c3v.z, xc0, tB0.z); tB0.w = fmaf(c3v.w, xc0, tB0.w);
                    tB1.x = fmaf(c3v.x, xc1, tB1.x); tB1.y = fmaf(c3v.y, xc1, tB1.y);
                    tB1.z = fmaf(c3v.z, xc1, tB1.z); tB1.w = fmaf(c3v.w, xc1, tB1.w);
                }
                tP0.x = fmaf(tB0.x, xb0, tP0.x); tP0.y = fmaf(tB0.y, xb0, tP0.y);
                tP0.z = fmaf(tB0.z, xb0, tP0.z); tP0.w = fmaf(tB0.w, xb0, tP0.w);
                tP1.x = fmaf(tB1.x, xb1, tP1.x); tP1.y = fmaf(tB1.y, xb1, tP1.y);
                tP1.z = fmaf(tB1.z, xb1, tP1.z); tP1.w = fmaf(tB1.w, xb1, tP1.w);
            }
            acc0.x = fmaf(tP0.x, xa0, acc0.x); acc0.y = fmaf(tP0.y, xa0, acc0.y);
            acc0.z = fmaf(tP0.z, xa0, acc0.z); acc0.w = fmaf(tP0.w, xa0, acc0.w);
            acc1.x = fmaf(tP1.x, xa1, acc1.x); acc1.y = fmaf(tP1.y, xa1, acc1.y);
            acc1.z = fmaf(tP1.z, xa1, acc1.z); acc1.w = fmaf(tP1.w, xa1, acc1.w);
        }
        if (act0) {
            float* o = outg + (size_t)n0*512;
            o[c] = acc0.x;
            o[128 + c*3 + 0] = acc0.y; o[128 + c*3 + 1] = acc0.z; o[128 + c*3 + 2] = acc0.w;
        }
        if (act1) {
            float* o = outg + (size_t)n1*512;
            o[c] = acc1.x;
            o[128 + c*3 + 0] = acc1.y; o[128 + c*3 + 1] = acc1.z; o[128 + c*3 + 2] = acc1.w;
        }
    }
}

extern "C" void kernel_launch(void* const* d_in, const int* in_sizes, int n_in,
                              void* d_out, int out_size, void* d_ws, size_t ws_size,
                              hipStream_t stream) {
    const float* x = (const float*)d_in[0];
    const float* y = (const float*)d_in[1];
    const float* U3_0 = (const float*)d_in[2];
    const float* U2_0 = (const float*)d_in[3];
    const float* U1_0 = (const float*)d_in[4];
    const float* W3_0 = (const float*)d_in[5];
    const float* W2_0 = (const float*)d_in[6];
    const float* W1_0 = (const float*)d_in[7];
    const float* U3_1 = (const float*)d_in[8];
    const float* U2_1 = (const float*)d_in[9];
    const float* U1_1 = (const float*)d_in[10];
    const float* W3_1 = (const float*)d_in[11];
    const float* W2_1 = (const float*)d_in[12];
    const float* W1_1 = (const float*)d_in[13];
    float* out = (float*)d_out;
    float* ws = (float*)d_ws;

    prep_sym<<<dim3(PREP_BLOCKS + EN), 256, 0, stream>>>(U3_0, U2_0, U3_1, U2_1, y, ws);
    if (ws_size >= WS_NEED_BYTES) {
        sc_build<<<dim3(NTT/8, EN), 128, 0, stream>>>(ws, (float4*)(ws + TALL_OFF),
                                                      U1_0, U1_1,
                                                      W3_0, W2_0, W1_0, W3_1, W2_1, W1_1);
        sc_apply<<<dim3(CN, EN), 64, 0, stream>>>(x, ws, out);
    } else {
        sc_main_fused<<<dim3(CN, EN), 128, 0, stream>>>(x, U1_0, U1_1,
                                                        W3_0, W2_0, W1_0,
                                                        W3_1, W2_1, W1_1, ws, out);
    }
}

// Round 8
// 209.339 us; speedup vs baseline: 1.0049x; 1.0049x over previous
//
#include <hip/hip_runtime.h>
#include <hip/hip_fp16.h>
#include <stdint.h>

// SymmetricContraction (MACE) on MI355X — symmetrized monomials, 3-kernel split.
//
// out[b,c,m] = sum_{a<=b<=cc} x_a x_b x_cc*T3 + sum_{a<=b} x_a x_b*T2 + sum_a x_a*T1
// Horner: out = sum_a x_a*( T1[a] + sum_{b>=a} x_b*( T2[ab] + sum_{cc>=b} x_cc*T3 ) )
// Irreps fused into 4 slots (0e | 1o m=0..2).
//
// R8 (from counters): R7's 4-node/64-thread variant was latency-bound (5
// waves/CU). Revert to R6 geometry (128 thr, 2 nodes/thread, 10 waves/CU,
// proven LDS-throughput-bound at 75us). LDS cycles scale with BYTES, so the
// coefficient table is now fp16 (4 x half = 8B/entry, uint2): coef reads
// become ds_read_b64 (6 cyc vs 12), halving the dominant LDS stream.
// x stays f32 (precision) as packed float2 pairs. Convert coef with
// v_cvt_f32_f16 in VALU (hidden under the LDS pipe bound).

#define BN 2048
#define CN 128
#define EN 10

#define NT3 816   // #sorted triples a<=b<=cc in [0,16)
#define NT2 136   // #sorted pairs a<=b
#define NTT (NT3 + NT2 + 16)   // 968 fused table entries
#define K3_0 23
#define K3_1 33
#define K2_0 4
#define K2_1 5

// ws layout (float offsets)
#define U3S0_OFF 0                          // [23][816]
#define U3S1_OFF (K3_0*NT3)                 // [3][33][816]
#define U2S0_OFF (U3S1_OFF + 3*K3_1*NT3)    // [4][136]
#define U2S1_OFF (U2S0_OFF + K2_0*NT2)      // [3][5][136]
#define LISTS_OFF (U2S1_OFF + 3*K2_1*NT2)   // int[10][2048]
#define CNT_OFF (LISTS_OFF + EN*BN)         // int[10]
#define TALL_OFF (((CNT_OFF + EN) + 3) & ~3)        // uint2[1280][968] (fp16 x4)
#define WS_NEED_BYTES ((size_t)TALL_OFF*4 + (size_t)EN*CN*NTT*8)

#define PREP_TOT (K3_0*NT3 + 3*K3_1*NT3 + K2_0*NT2 + 3*K2_1*NT2)  // 102136
#define PREP_BLOCKS ((PREP_TOT + 255) / 256)                       // 400

typedef float v2f __attribute__((ext_vector_type(2)));
#define FMA2(a, b, c) __builtin_elementwise_fma((a), (b), (c))
static __device__ __forceinline__ v2f splat2(float v) { v2f r; r.x = v; r.y = v; return r; }

__global__ __launch_bounds__(256) void prep_sym(
    const float* __restrict__ U3_0, const float* __restrict__ U2_0,
    const float* __restrict__ U3_1, const float* __restrict__ U2_1,
    const float* __restrict__ yg, float* __restrict__ ws)
{
    const int bid = blockIdx.x, tid = threadIdx.x;
    if (bid < PREP_BLOCKS) {
        const int N0 = K3_0*NT3, N1 = 3*K3_1*NT3, P0 = K2_0*NT2;
        const int it = bid*256 + tid;
        if (it >= PREP_TOT) return;
        if (it < N0 + N1) {
            const float* U3; int m, k, K, t, dst;
            if (it < N0) { U3 = U3_0; K = K3_0; m = 0; k = it / NT3; t = it - k*NT3; dst = U3S0_OFF + it; }
            else { int r = it - N0; U3 = U3_1; K = K3_1; int mk = r / NT3; t = r - mk*NT3;
                   m = mk / K3_1; k = mk - m*K3_1; dst = U3S1_OFF + r; }
            // unrank t -> (a<=b<=cc), lexicographic (matches sc_apply loop order)
            int a = 0, rem = t;
            while (rem >= ((16-a)*(17-a))/2) { rem -= ((16-a)*(17-a))/2; ++a; }
            int b = a;
            while (rem >= 16-b) { rem -= 16-b; ++b; }
            const int cc = b + rem;
            #define AT3(i,j,l) U3[(size_t)(((m*16+(i))*16+(j))*16+(l))*K + k]
            float D = AT3(a,b,cc) + AT3(a,cc,b) + AT3(b,a,cc)
                    + AT3(b,cc,a) + AT3(cc,a,b) + AT3(cc,b,a);
            #undef AT3
            const int eq = (a==b) + (b==cc);
            D *= (eq==2) ? (1.f/6.f) : (eq==1) ? 0.5f : 1.f;
            ws[dst] = D;
        } else {
            const int it2 = it - (N0+N1);
            const float* U2; int m, k, K, pr, dst;
            if (it2 < P0) { U2 = U2_0; K = K2_0; m = 0; k = it2 / NT2; pr = it2 - k*NT2; dst = U2S0_OFF + it2; }
            else { int r = it2 - P0; U2 = U2_1; K = K2_1; int mk = r / NT2; pr = r - mk*NT2;
                   m = mk / K2_1; k = mk - m*K2_1; dst = U2S1_OFF + r; }
            int a = 0, rem = pr;
            while (rem >= 16-a) { rem -= 16-a; ++a; }
            const int b = a + rem;
            float D = U2[(size_t)((m*16+a)*16+b)*K + k]
                    + U2[(size_t)((m*16+b)*16+a)*K + k];
            if (a == b) D *= 0.5f;
            ws[dst] = D;
        }
    } else if (bid < PREP_BLOCKS + EN) {
        const int e = bid - PREP_BLOCKS;
        __shared__ int lcnt;
        if (tid == 0) lcnt = 0;
        __syncthreads();
        int* lists = (int*)(ws + LISTS_OFF);
        for (int b = tid; b < BN; b += 256) {
            if (yg[b*EN + e] > 0.5f) {
                int p = atomicAdd(&lcnt, 1);
                lists[e*BN + p] = b;
            }
        }
        __syncthreads();
        if (tid == 0) ((int*)(ws + CNT_OFF))[e] = lcnt;
    }
}

static __device__ __forceinline__ uint2 pack_h4(float a0, float a1, float a2, float a3) {
    __half2 lo = __floats2half2_rn(a0, a1);
    __half2 hi = __floats2half2_rn(a2, a3);
    uint2 r;
    r.x = *reinterpret_cast<const unsigned int*>(&lo);
    r.y = *reinterpret_cast<const unsigned int*>(&hi);
    return r;
}

// ---- fused tables (fp16 x4 per entry): block=(8-g chunk, e), thread=c ----
__global__ __launch_bounds__(128) void sc_build(
    const float* __restrict__ usym, uint2* __restrict__ tall,
    const float* __restrict__ U1_0, const float* __restrict__ U1_1,
    const float* __restrict__ W3_0, const float* __restrict__ W2_0, const float* __restrict__ W1_0,
    const float* __restrict__ W3_1, const float* __restrict__ W2_1, const float* __restrict__ W1_1)
{
    const int g0 = blockIdx.x * 8;
    const int e = blockIdx.y;
    const int c = threadIdx.x;
    uint2* out8 = tall + (size_t)(e*CN + c)*NTT;

    if (g0 < NT3) {
        float w0[K3_0], w1[K3_1];
#pragma unroll
        for (int k = 0; k < K3_0; ++k) w0[k] = W3_0[(e*K3_0 + k)*CN + c];
#pragma unroll
        for (int k = 0; k < K3_1; ++k) w1[k] = W3_1[(e*K3_1 + k)*CN + c];
        const float* u0 = usym + U3S0_OFF;
        const float* u1 = usym + U3S1_OFF;
#pragma unroll 2
        for (int j = 0; j < 8; ++j) {
            const int g = g0 + j;
            float a0 = 0.f, a1 = 0.f, a2 = 0.f, a3 = 0.f;
#pragma unroll
            for (int k = 0; k < K3_0; ++k) a0 = fmaf(u0[k*NT3 + g], w0[k], a0);
#pragma unroll
            for (int k = 0; k < K3_1; ++k) {
                a1 = fmaf(u1[k*NT3 + g], w1[k], a1);
                a2 = fmaf(u1[(K3_1 + k)*NT3 + g], w1[k], a2);
                a3 = fmaf(u1[(2*K3_1 + k)*NT3 + g], w1[k], a3);
            }
            out8[g] = pack_h4(a0, a1, a2, a3);
        }
    } else if (g0 < NT3 + NT2) {
        float w0[K2_0], w1[K2_1];
#pragma unroll
        for (int k = 0; k < K2_0; ++k) w0[k] = W2_0[(e*K2_0 + k)*CN + c];
#pragma unroll
        for (int k = 0; k < K2_1; ++k) w1[k] = W2_1[(e*K2_1 + k)*CN + c];
        const float* u0 = usym + U2S0_OFF;
        const float* u1 = usym + U2S1_OFF;
#pragma unroll
        for (int j = 0; j < 8; ++j) {
            const int g = g0 + j;
            const int pr = g - NT3;
            float a0 = 0.f, a1 = 0.f, a2 = 0.f, a3 = 0.f;
#pragma unroll
            for (int k = 0; k < K2_0; ++k) a0 = fmaf(u0[k*NT2 + pr], w0[k], a0);
#pragma unroll
            for (int k = 0; k < K2_1; ++k) {
                a1 = fmaf(u1[k*NT2 + pr], w1[k], a1);
                a2 = fmaf(u1[(K2_1 + k)*NT2 + pr], w1[k], a2);
                a3 = fmaf(u1[(2*K2_1 + k)*NT2 + pr], w1[k], a3);
            }
            out8[g] = pack_h4(a0, a1, a2, a3);
        }
    } else {
        const float w10 = W1_0[e*CN + c];
        const float w11 = W1_1[e*CN + c];
#pragma unroll
        for (int j = 0; j < 8; ++j) {
            const int g = g0 + j;
            const int a = g - (NT3 + NT2);
            out8[g] = pack_h4(U1_0[a]*w10, U1_1[a]*w11,
                              U1_1[16+a]*w11, U1_1[32+a]*w11);
        }
    }
}

// ---- node loop (R6 geometry): 128 thr, 2 nodes/thread packed float2 in LDS,
// fp16 coef table in LDS (b64 broadcast), cvt in VALU, pk-fma math.
__global__ __launch_bounds__(128) void sc_apply(
    const float* __restrict__ xg, const float* __restrict__ ws,
    float* __restrict__ outg)
{
    const int c = blockIdx.x, e = blockIdx.y, tid = threadIdx.x;
    __shared__ uint2 Tsh[NTT];     // 7744 B fp16 table
    __shared__ v2f xs[16*128];     // 16384 B: row i, pair column per thread

    const uint2* __restrict__ tG =
        (const uint2*)(ws + TALL_OFF) + (size_t)(e*CN + c)*NTT;
    for (int i = tid; i < NTT; i += 128) Tsh[i] = tG[i];

    const int* lists = (const int*)(ws + LISTS_OFF) + e*BN;
    const int cnt = ((const int*)(ws + CNT_OFF))[e];
    __syncthreads();

    for (int base = 0; base < cnt; base += 256) {
        const int s0 = base + tid, s1 = base + tid + 128;
        const bool act0 = s0 < cnt, act1 = s1 < cnt;
        const int n0 = lists[act0 ? s0 : 0];
        const int n1 = lists[act1 ? s1 : 0];
        const float4* p0 = (const float4*)(xg + ((size_t)n0*CN + c)*16);
        const float4* p1 = (const float4*)(xg + ((size_t)n1*CN + c)*16);
#pragma unroll
        for (int d = 0; d < 4; ++d) {
            const float4 v0 = p0[d]; const float4 v1 = p1[d];
            v2f w;
            w.x = v0.x; w.y = v1.x; xs[(4*d+0)*128+tid] = w;
            w.x = v0.y; w.y = v1.y; xs[(4*d+1)*128+tid] = w;
            w.x = v0.z; w.y = v1.z; xs[(4*d+2)*128+tid] = w;
            w.x = v0.w; w.y = v1.w; xs[(4*d+3)*128+tid] = w;
        }
        // xs columns are thread-private: no barrier anywhere.

        v2f acc0 = splat2(0.f), acc1 = acc0, acc2 = acc0, acc3 = acc0;
        int t3 = 0, t2 = NT3;
#pragma unroll 1
        for (int a = 0; a < 16; ++a) {
            const v2f xa = xs[a*128+tid];
            const uint2 t1w = Tsh[NT3 + NT2 + a];
            const float2 t1lo = __half22float2(*reinterpret_cast<const __half2*>(&t1w.x));
            const float2 t1hi = __half22float2(*reinterpret_cast<const __half2*>(&t1w.y));
            v2f tP0 = splat2(t1lo.x), tP1 = splat2(t1lo.y),
                tP2 = splat2(t1hi.x), tP3 = splat2(t1hi.y);
#pragma unroll 1
            for (int b = a; b < 16; ++b) {
                const v2f xb = xs[b*128+tid];
                const uint2 c2w = Tsh[t2]; ++t2;
                const float2 c2lo = __half22float2(*reinterpret_cast<const __half2*>(&c2w.x));
                const float2 c2hi = __half22float2(*reinterpret_cast<const __half2*>(&c2w.y));
                v2f tB0 = splat2(c2lo.x), tB1 = splat2(c2lo.y),
                    tB2 = splat2(c2hi.x), tB3 = splat2(c2hi.y);
#pragma unroll 4
                for (int cc = b; cc < 16; ++cc) {
                    const v2f xc = xs[cc*128+tid];
                    const uint2 c3w = Tsh[t3]; ++t3;
                    const float2 c3lo = __half22float2(*reinterpret_cast<const __half2*>(&c3w.x));
                    const float2 c3hi = __half22float2(*reinterpret_cast<const __half2*>(&c3w.y));
                    tB0 = FMA2(splat2(c3lo.x), xc, tB0);
                    tB1 = FMA2(splat2(c3lo.y), xc, tB1);
                    tB2 = FMA2(splat2(c3hi.x), xc, tB2);
                    tB3 = FMA2(splat2(c3hi.y), xc, tB3);
                }
                tP0 = FMA2(tB0, xb, tP0);
                tP1 = FMA2(tB1, xb, tP1);
                tP2 = FMA2(tB2, xb, tP2);
                tP3 = FMA2(tB3, xb, tP3);
            }
            acc0 = FMA2(tP0, xa, acc0);
            acc1 = FMA2(tP1, xa, acc1);
            acc2 = FMA2(tP2, xa, acc2);
            acc3 = FMA2(tP3, xa, acc3);
        }
        if (act0) {
            float* o = outg + (size_t)n0*512;
            o[c] = acc0.x;
            o[128 + c*3 + 0] = acc1.x; o[128 + c*3 + 1] = acc2.x; o[128 + c*3 + 2] = acc3.x;
        }
        if (act1) {
            float* o = outg + (size_t)n1*512;
            o[c] = acc0.y;
            o[128 + c*3 + 0] = acc1.y; o[128 + c*3 + 1] = acc2.y; o[128 + c*3 + 2] = acc3.y;
        }
    }
}

// ---- fallback (proven R2 fused kernel, all-f32): used only if ws too small
__global__ __launch_bounds__(128) void sc_main_fused(
    const float* __restrict__ xg,
    const float* __restrict__ U1_0, const float* __restrict__ U1_1,
    const float* __restrict__ W3_0, const float* __restrict__ W2_0, const float* __restrict__ W1_0,
    const float* __restrict__ W3_1, const float* __restrict__ W2_1, const float* __restrict__ W1_1,
    const float* __restrict__ ws, float* __restrict__ outg)
{
    const int c = blockIdx.x, e = blockIdx.y, tid = threadIdx.x;
    __shared__ float4 T3s[NT3];
    __shared__ float4 T2s[NT2];
    __shared__ float4 T1s[16];
    __shared__ float xs0[16*128];
    __shared__ float xs1[16*128];
    __shared__ float wk30s[K3_0], wk31s[K3_1], wk20s[K2_0], wk21s[K2_1];

    if (tid < K3_0) wk30s[tid] = W3_0[(e*K3_0 + tid)*CN + c];
    if (tid >= 32 && tid < 32 + K3_1) wk31s[tid-32] = W3_1[(e*K3_1 + (tid-32))*CN + c];
    if (tid >= 72 && tid < 72 + K2_0) wk20s[tid-72] = W2_0[(e*K2_0 + (tid-72))*CN + c];
    if (tid >= 80 && tid < 80 + K2_1) wk21s[tid-80] = W2_1[(e*K2_1 + (tid-80))*CN + c];
    __syncthreads();

    const float* u3s0 = ws + U3S0_OFF;
    const float* u3s1 = ws + U3S1_OFF;
    for (int g = tid; g < NT3/4; g += 128) {
        float4 A0 = make_float4(0,0,0,0), A1 = A0, A2 = A0, A3 = A0;
#pragma unroll
        for (int k = 0; k < K3_0; ++k) {
            const float w = wk30s[k];
            const float4 u = ((const float4*)(u3s0 + k*NT3))[g];
            A0.x = fmaf(u.x, w, A0.x); A0.y = fmaf(u.y, w, A0.y);
            A0.z = fmaf(u.z, w, A0.z); A0.w = fmaf(u.w, w, A0.w);
        }
#pragma unroll 8
        for (int k = 0; k < K3_1; ++k) {
            const float w = wk31s[k];
            const float4 ua = ((const float4*)(u3s1 + k*NT3))[g];
            A1.x = fmaf(ua.x, w, A1.x); A1.y = fmaf(ua.y, w, A1.y);
            A1.z = fmaf(ua.z, w, A1.z); A1.w = fmaf(ua.w, w, A1.w);
            const float4 ub = ((const float4*)(u3s1 + (K3_1 + k)*NT3))[g];
            A2.x = fmaf(ub.x, w, A2.x); A2.y = fmaf(ub.y, w, A2.y);
            A2.z = fmaf(ub.z, w, A2.z); A2.w = fmaf(ub.w, w, A2.w);
            const float4 uc = ((const float4*)(u3s1 + (2*K3_1 + k)*NT3))[g];
            A3.x = fmaf(uc.x, w, A3.x); A3.y = fmaf(uc.y, w, A3.y);
            A3.z = fmaf(uc.z, w, A3.z); A3.w = fmaf(uc.w, w, A3.w);
        }
        T3s[4*g+0] = make_float4(A0.x, A1.x, A2.x, A3.x);
        T3s[4*g+1] = make_float4(A0.y, A1.y, A2.y, A3.y);
        T3s[4*g+2] = make_float4(A0.z, A1.z, A2.z, A3.z);
        T3s[4*g+3] = make_float4(A0.w, A1.w, A2.w, A3.w);
    }
    const float* u2s0 = ws + U2S0_OFF;
    const float* u2s1 = ws + U2S1_OFF;
    for (int g = tid; g < NT2/4; g += 128) {
        float4 A0 = make_float4(0,0,0,0), A1 = A0, A2 = A0, A3 = A0;
#pragma unroll
        for (int k = 0; k < K2_0; ++k) {
            const float w = wk20s[k];
            const float4 u = ((const float4*)(u2s0 + k*NT2))[g];
            A0.x = fmaf(u.x, w, A0.x); A0.y = fmaf(u.y, w, A0.y);
            A0.z = fmaf(u.z, w, A0.z); A0.w = fmaf(u.w, w, A0.w);
        }
#pragma unroll
        for (int k = 0; k < K2_1; ++k) {
            const float w = wk21s[k];
            const float4 ua = ((const float4*)(u2s1 + k*NT2))[g];
            A1.x = fmaf(ua.x, w, A1.x); A1.y = fmaf(ua.y, w, A1.y);
            A1.z = fmaf(ua.z, w, A1.z); A1.w = fmaf(ua.w, w, A1.w);
            const float4 ub = ((const float4*)(u2s1 + (K2_1 + k)*NT2))[g];
            A2.x = fmaf(ub.x, w, A2.x); A2.y = fmaf(ub.y, w, A2.y);
            A2.z = fmaf(ub.z, w, A2.z); A2.w = fmaf(ub.w, w, A2.w);
            const float4 uc = ((const float4*)(u2s1 + (2*K2_1 + k)*NT2))[g];
            A3.x = fmaf(uc.x, w, A3.x); A3.y = fmaf(uc.y, w, A3.y);
            A3.z = fmaf(uc.z, w, A3.z); A3.w = fmaf(uc.w, w, A3.w);
        }
        T2s[4*g+0] = make_float4(A0.x, A1.x, A2.x, A3.x);
        T2s[4*g+1] = make_float4(A0.y, A1.y, A2.y, A3.y);
        T2s[4*g+2] = make_float4(A0.z, A1.z, A2.z, A3.z);
        T2s[4*g+3] = make_float4(A0.w, A1.w, A2.w, A3.w);
    }
    if (tid < 16) {
        const float wk10 = W1_0[e*CN + c];
        const float wk11 = W1_1[e*CN + c];
        const int j = tid;
        T1s[j] = make_float4(U1_0[j]*wk10, U1_1[j]*wk11,
                             U1_1[16+j]*wk11, U1_1[32+j]*wk11);
    }

    const int* lists = (const int*)(ws + LISTS_OFF) + e*BN;
    const int cnt = ((const int*)(ws + CNT_OFF))[e];
    __syncthreads();

    for (int base = 0; base < cnt; base += 256) {
        const int s0 = base + tid, s1 = base + tid + 128;
        const bool act0 = s0 < cnt, act1 = s1 < cnt;
        const int n0 = lists[act0 ? s0 : 0];
        const int n1 = lists[act1 ? s1 : 0];
        const float4* p0 = (const float4*)(xg + ((size_t)n0*CN + c)*16);
        const float4* p1 = (const float4*)(xg + ((size_t)n1*CN + c)*16);
#pragma unroll
        for (int d = 0; d < 4; ++d) {
            const float4 v0 = p0[d]; const float4 v1 = p1[d];
            xs0[(4*d+0)*128+tid] = v0.x; xs0[(4*d+1)*128+tid] = v0.y;
            xs0[(4*d+2)*128+tid] = v0.z; xs0[(4*d+3)*128+tid] = v0.w;
            xs1[(4*d+0)*128+tid] = v1.x; xs1[(4*d+1)*128+tid] = v1.y;
            xs1[(4*d+2)*128+tid] = v1.z; xs1[(4*d+3)*128+tid] = v1.w;
        }
        float4 acc0 = make_float4(0,0,0,0), acc1 = acc0;
        int t3 = 0, t2i = 0;
#pragma unroll 1
        for (int a = 0; a < 16; ++a) {
            const float xa0 = xs0[a*128+tid];
            const float xa1 = xs1[a*128+tid];
            float4 tP0 = T1s[a], tP1 = tP0;
#pragma unroll 1
            for (int b = a; b < 16; ++b) {
                const float xb0 = xs0[b*128+tid];
                const float xb1 = xs1[b*128+tid];
                const float4 c2v = T2s[t2i]; ++t2i;
                float4 tB0 = c2v, tB1 = c2v;
#pragma unroll 4
                for (int cc = b; cc < 16; ++cc) {
                    const float xc0 = xs0[cc*128+tid];
                    const float xc1 = xs1[cc*128+tid];
                    const float4 c3v = T3s[t3]; ++t3;
                    tB0.x = fmaf(c3v.x, xc0, tB0.x); tB0.y = fmaf(c3v.y, xc0, tB0.y);
                    tB0.z = fmaf(c3v.z, xc0, tB0.z); tB0.w = fmaf(c3v.w, xc0, tB0.w);
                    tB1.x = fmaf(c3v.x, xc1, tB1.x); tB1.y = fmaf(c3v.y, xc1, tB1.y);
                    tB1.z = fmaf(c3v.z, xc1, tB1.z); tB1.w = fmaf(c3v.w, xc1, tB1.w);
                }
                tP0.x = fmaf(tB0.x, xb0, tP0.x); tP0.y = fmaf(tB0.y, xb0, tP0.y);
                tP0.z = fmaf(tB0.z, xb0, tP0.z); tP0.w = fmaf(tB0.w, xb0, tP0.w);
                tP1.x = fmaf(tB1.x, xb1, tP1.x); tP1.y = fmaf(tB1.y, xb1, tP1.y);
                tP1.z = fmaf(tB1.z, xb1, tP1.z); tP1.w = fmaf(tB1.w, xb1, tP1.w);
            }
            acc0.x = fmaf(tP0.x, xa0, acc0.x); acc0.y = fmaf(tP0.y, xa0, acc0.y);
            acc0.z = fmaf(tP0.z, xa0, acc0.z); acc0.w = fmaf(tP0.w, xa0, acc0.w);
            acc1.x = fmaf(tP1.x, xa1, acc1.x); acc1.y = fmaf(tP1.y, xa1, acc1.y);
            acc1.z = fmaf(tP1.z, xa1, acc1.z); acc1.w = fmaf(tP1.w, xa1, acc1.w);
        }
        if (act0) {
            float* o = outg + (size_t)n0*512;
            o[c] = acc0.x;
            o[128 + c*3 + 0] = acc0.y; o[128 + c*3 + 1] = acc0.z; o[128 + c*3 + 2] = acc0.w;
        }
        if (act1) {
            float* o = outg + (size_t)n1*512;
            o[c] = acc1.x;
            o[128 + c*3 + 0] = acc1.y; o[128 + c*3 + 1] = acc1.z; o[128 + c*3 + 2] = acc1.w;
        }
    }
}

extern "C" void kernel_launch(void* const* d_in, const int* in_sizes, int n_in,
                              void* d_out, int out_size, void* d_ws, size_t ws_size,
                              hipStream_t stream) {
    const float* x = (const float*)d_in[0];
    const float* y = (const float*)d_in[1];
    const float* U3_0 = (const float*)d_in[2];
    const float* U2_0 = (const float*)d_in[3];
    const float* U1_0 = (const float*)d_in[4];
    const float* W3_0 = (const float*)d_in[5];
    const float* W2_0 = (const float*)d_in[6];
    const float* W1_0 = (const float*)d_in[7];
    const float* U3_1 = (const float*)d_in[8];
    const float* U2_1 = (const float*)d_in[9];
    const float* U1_1 = (const float*)d_in[10];
    const float* W3_1 = (const float*)d_in[11];
    const float* W2_1 = (const float*)d_in[12];
    const float* W1_1 = (const float*)d_in[13];
    float* out = (float*)d_out;
    float* ws = (float*)d_ws;

    prep_sym<<<dim3(PREP_BLOCKS + EN), 256, 0, stream>>>(U3_0, U2_0, U3_1, U2_1, y, ws);
    if (ws_size >= WS_NEED_BYTES) {
        sc_build<<<dim3(NTT/8, EN), 128, 0, stream>>>(ws, (uint2*)(ws + TALL_OFF),
                                                      U1_0, U1_1,
                                                      W3_0, W2_0, W1_0, W3_1, W2_1, W1_1);
        sc_apply<<<dim3(CN, EN), 128, 0, stream>>>(x, ws, out);
    } else {
        sc_main_fused<<<dim3(CN, EN), 128, 0, stream>>>(x, U1_0, U1_1,
                                                        W3_0, W2_0, W1_0,
                                                        W3_1, W2_1, W1_1, ws, out);
    }
}